// Round 13
// baseline (1119.870 us; speedup 1.0000x reference)
//
#include <hip/hip_runtime.h>
#include <math.h>

// Problem constants (from reference)
#define DMODEL 1024
#define NHEAD  16
#define HD     64
#define DFF    4096
#define SEQ    2048
#define BATCH  2
#define NTOK   (BATCH * SEQ)   // 4096
#define LN_EPS 1e-5f

typedef __attribute__((ext_vector_type(8))) short short8;
typedef __attribute__((ext_vector_type(4))) float floatx4;
typedef __attribute__((ext_vector_type(4))) unsigned short ushort4v;

// ---- bf16 split helpers: x = hi + lo, both bf16 (RNE) --------------------
__device__ __forceinline__ unsigned short f2bf(float x) {
  unsigned int u = __float_as_uint(x);
  return (unsigned short)((u + 0x7FFFu + ((u >> 16) & 1u)) >> 16);
}
__device__ __forceinline__ float bf2f(unsigned short h) {
  return __uint_as_float(((unsigned int)h) << 16);
}
__device__ __forceinline__ void split2(float x, unsigned short& hi, unsigned short& lo) {
  hi = f2bf(x);
  lo = f2bf(x - bf2f(hi));
}

// ---------------------------------------------------------------------------
// LayerNorm: one block per row (D=1024), 256 threads x float4.
// Writes split-bf16 (hi, lo) outputs for the MFMA GEMMs.
// ---------------------------------------------------------------------------
__global__ __launch_bounds__(256) void ln_split(
    const float* __restrict__ x, const float* __restrict__ g,
    const float* __restrict__ beta, short* __restrict__ ohi,
    short* __restrict__ olo) {
  int row = blockIdx.x;
  const float4* xr = (const float4*)(x + (size_t)row * DMODEL);
  float4 v = xr[threadIdx.x];
  float s  = v.x + v.y + v.z + v.w;
  float sq = v.x * v.x + v.y * v.y + v.z * v.z + v.w * v.w;
#pragma unroll
  for (int off = 1; off < 64; off <<= 1) {
    s  += __shfl_xor(s, off);
    sq += __shfl_xor(sq, off);
  }
  __shared__ float red_s[4], red_q[4];
  int wave = threadIdx.x >> 6, lane = threadIdx.x & 63;
  if (lane == 0) { red_s[wave] = s; red_q[wave] = sq; }
  __syncthreads();
  s  = red_s[0] + red_s[1] + red_s[2] + red_s[3];
  sq = red_q[0] + red_q[1] + red_q[2] + red_q[3];
  float mu  = s * (1.0f / DMODEL);
  float var = sq * (1.0f / DMODEL) - mu * mu;
  float r   = rsqrtf(var + LN_EPS);
  float4 gv = ((const float4*)g)[threadIdx.x];
  float4 bv = ((const float4*)beta)[threadIdx.x];
  float o0 = (v.x - mu) * r * gv.x + bv.x;
  float o1 = (v.y - mu) * r * gv.y + bv.y;
  float o2 = (v.z - mu) * r * gv.z + bv.z;
  float o3 = (v.w - mu) * r * gv.w + bv.w;
  ushort4v hi, lo;
  unsigned short h_, l_;
  split2(o0, h_, l_); hi.x = h_; lo.x = l_;
  split2(o1, h_, l_); hi.y = h_; lo.y = l_;
  split2(o2, h_, l_); hi.z = h_; lo.z = l_;
  split2(o3, h_, l_); hi.w = h_; lo.w = l_;
  size_t base = (size_t)row * DMODEL + threadIdx.x * 4;
  *(ushort4v*)(ohi + base) = hi;
  *(ushort4v*)(olo + base) = lo;
}

// ---------------------------------------------------------------------------
// Elementwise split: fp32 -> (hi, lo) bf16. 4 floats/thread.
// ---------------------------------------------------------------------------
__global__ __launch_bounds__(256) void split_rows(
    const float* __restrict__ in, short* __restrict__ ohi,
    short* __restrict__ olo) {
  size_t i = ((size_t)blockIdx.x * 256 + threadIdx.x) * 4;
  float4 v = *(const float4*)(in + i);
  ushort4v hi, lo;
  unsigned short h_, l_;
  split2(v.x, h_, l_); hi.x = h_; lo.x = l_;
  split2(v.y, h_, l_); hi.y = h_; lo.y = l_;
  split2(v.z, h_, l_); hi.z = h_; lo.z = l_;
  split2(v.w, h_, l_); hi.w = h_; lo.w = l_;
  *(ushort4v*)(ohi + i) = hi;
  *(ushort4v*)(olo + i) = lo;
}

// ---------------------------------------------------------------------------
// Build transposed+split QKV weight: WcT[col][d], col = m*1024 + h*64 + k.
// ---------------------------------------------------------------------------
__global__ __launch_bounds__(256) void repack_qkvT(
    const float* __restrict__ Wq, const float* __restrict__ Wk,
    const float* __restrict__ Wv, short* __restrict__ ohi,
    short* __restrict__ olo) {
  int i = blockIdx.x * 256 + threadIdx.x;  // over 3072*1024
  int col = i >> 10;
  int d   = i & 1023;
  int m   = col >> 10;
  int c   = col & 1023;
  const float* W = (m == 0) ? Wq : (m == 1 ? Wk : Wv);
  int hh = c >> 6, kk = c & 63;
  float w = W[((size_t)hh * DMODEL + d) * HD + kk];
  unsigned short h_, l_;
  split2(w, h_, l_);
  ohi[i] = (short)h_;
  olo[i] = (short)l_;
}

// ---------------------------------------------------------------------------
// Generic transpose + split: in[R][C] fp32 -> out[C][R] bf16 hi/lo.
// ---------------------------------------------------------------------------
__global__ __launch_bounds__(256) void transpose_split(
    const float* __restrict__ in, short* __restrict__ ohi,
    short* __restrict__ olo, int lgR, int C) {
  int i = blockIdx.x * 256 + threadIdx.x;  // over C*R
  int R = 1 << lgR;
  int oc = i >> lgR;        // 0..C-1  (output row = original col)
  int orow = i & (R - 1);   // 0..R-1
  float w = in[(size_t)orow * C + oc];
  unsigned short h_, l_;
  split2(w, h_, l_);
  ohi[i] = (short)h_;
  olo[i] = (short)l_;
}

// ---------------------------------------------------------------------------
// V transpose: qkv split-bf16 [tok][3072] V-section -> Vt[b][h][d][s].
// LDS-tiled 64x64 per (s-tile, h, b); all global R/W vectorized short8.
// ---------------------------------------------------------------------------
__global__ __launch_bounds__(256) void vt_transpose(
    const short* __restrict__ qkvh, const short* __restrict__ qkvl,
    short* __restrict__ vth, short* __restrict__ vtl) {
  int st = blockIdx.x;  // SEQ/64 tiles
  int h = blockIdx.y, b = blockIdx.z;
  __shared__ short Th[64][72];
  __shared__ short Tl[64][72];
  int tid = threadIdx.x;
  {
    int sl = tid >> 2, d0 = (tid & 3) * 16;
    const short* ph = qkvh + (size_t)(b * SEQ + st * 64 + sl) * 3072 + 2048 + h * HD + d0;
    const short* pl = qkvl + (size_t)(b * SEQ + st * 64 + sl) * 3072 + 2048 + h * HD + d0;
    *(short8*)&Th[sl][d0]     = *(const short8*)ph;
    *(short8*)&Th[sl][d0 + 8] = *(const short8*)(ph + 8);
    *(short8*)&Tl[sl][d0]     = *(const short8*)pl;
    *(short8*)&Tl[sl][d0 + 8] = *(const short8*)(pl + 8);
  }
  __syncthreads();
  {
    int dl = tid >> 2, s0 = (tid & 3) * 16;
    short8 oh0, oh1, ol0, ol1;
#pragma unroll
    for (int j = 0; j < 8; j++) {
      oh0[j] = Th[s0 + j][dl];
      oh1[j] = Th[s0 + 8 + j][dl];
      ol0[j] = Tl[s0 + j][dl];
      ol1[j] = Tl[s0 + 8 + j][dl];
    }
    size_t obase = ((size_t)((b * NHEAD + h) * HD + dl)) * SEQ + st * 64 + s0;
    *(short8*)(vth + obase)     = oh0;
    *(short8*)(vth + obase + 8) = oh1;
    *(short8*)(vtl + obase)     = ol0;
    *(short8*)(vtl + obase + 8) = ol1;
  }
}

// ---------------------------------------------------------------------------
// Split-bf16 MFMA GEMM (measured round 7/11/12). Epilogues:
// 0 = fp32 store; 1 = +bias+res fp32; 2 = +bias, ReLU, split-bf16;
// 3 = split-bf16 store (no bias).
// ---------------------------------------------------------------------------
template <int MODE>
__global__ __launch_bounds__(256) void gemm_mfma(
    const short* __restrict__ Ahi, const short* __restrict__ Alo,
    const short* __restrict__ Bhi, const short* __restrict__ Blo,
    const float* __restrict__ bias, const float* __restrict__ res,
    float* __restrict__ Cf, short* __restrict__ Chi, short* __restrict__ Clo,
    int M, int N, int K) {
  __shared__ short As[2][128][40];  // [hi/lo][row][k(pad 40)]
  __shared__ short Bs[2][128][40];  // [hi/lo][col][k(pad 40)]
  int tid = threadIdx.x;
  int wv = tid >> 6, lane = tid & 63;
  int wr = (wv >> 1) * 64;
  int wc = (wv & 1) * 64;
  int m0 = blockIdx.y * 128, n0 = blockIdx.x * 128;

  int srow = tid >> 1;
  int soff = (tid & 1) * 16;
  const short* pAh = Ahi + (size_t)(m0 + srow) * K + soff;
  const short* pAl = Alo + (size_t)(m0 + srow) * K + soff;
  const short* pBh = Bhi + (size_t)(n0 + srow) * K + soff;
  const short* pBl = Blo + (size_t)(n0 + srow) * K + soff;

  int fr = lane & 15;
  int ko = (lane >> 4) * 8;

  floatx4 acc[4][4];
#pragma unroll
  for (int i = 0; i < 4; i++)
#pragma unroll
    for (int j = 0; j < 4; j++) acc[i][j] = (floatx4){0.f, 0.f, 0.f, 0.f};

  for (int k0 = 0; k0 < K; k0 += 32) {
    short8 ga0 = *(const short8*)(pAh + k0);
    short8 ga1 = *(const short8*)(pAh + k0 + 8);
    short8 gb0 = *(const short8*)(pAl + k0);
    short8 gb1 = *(const short8*)(pAl + k0 + 8);
    short8 gc0 = *(const short8*)(pBh + k0);
    short8 gc1 = *(const short8*)(pBh + k0 + 8);
    short8 gd0 = *(const short8*)(pBl + k0);
    short8 gd1 = *(const short8*)(pBl + k0 + 8);
    __syncthreads();
    *(short8*)&As[0][srow][soff]     = ga0;
    *(short8*)&As[0][srow][soff + 8] = ga1;
    *(short8*)&As[1][srow][soff]     = gb0;
    *(short8*)&As[1][srow][soff + 8] = gb1;
    *(short8*)&Bs[0][srow][soff]     = gc0;
    *(short8*)&Bs[0][srow][soff + 8] = gc1;
    *(short8*)&Bs[1][srow][soff]     = gd0;
    *(short8*)&Bs[1][srow][soff + 8] = gd1;
    __syncthreads();

    short8 ah[4], al[4], bh[4], bl[4];
#pragma unroll
    for (int i = 0; i < 4; i++) {
      ah[i] = *(const short8*)&As[0][wr + i * 16 + fr][ko];
      al[i] = *(const short8*)&As[1][wr + i * 16 + fr][ko];
      bh[i] = *(const short8*)&Bs[0][wc + i * 16 + fr][ko];
      bl[i] = *(const short8*)&Bs[1][wc + i * 16 + fr][ko];
    }
#pragma unroll
    for (int i = 0; i < 4; i++)
#pragma unroll
      for (int j = 0; j < 4; j++) {
        acc[i][j] = __builtin_amdgcn_mfma_f32_16x16x32_bf16(ah[i], bh[j], acc[i][j], 0, 0, 0);
        acc[i][j] = __builtin_amdgcn_mfma_f32_16x16x32_bf16(ah[i], bl[j], acc[i][j], 0, 0, 0);
        acc[i][j] = __builtin_amdgcn_mfma_f32_16x16x32_bf16(al[i], bh[j], acc[i][j], 0, 0, 0);
      }
  }

  int r4 = (lane >> 4) * 4;
#pragma unroll
  for (int i = 0; i < 4; i++)
#pragma unroll
    for (int j = 0; j < 4; j++)
#pragma unroll
      for (int r = 0; r < 4; r++) {
        int row = m0 + wr + i * 16 + r4 + r;
        int col = n0 + wc + j * 16 + fr;
        float v = acc[i][j][r];
        if (MODE == 0) {
          Cf[(size_t)row * N + col] = v;
        } else if (MODE == 1) {
          Cf[(size_t)row * N + col] = v + bias[col] + res[(size_t)row * N + col];
        } else if (MODE == 2) {
          v = fmaxf(v + bias[col], 0.f);
          unsigned short h_, l_;
          split2(v, h_, l_);
          Chi[(size_t)row * N + col] = (short)h_;
          Clo[(size_t)row * N + col] = (short)l_;
        } else {
          unsigned short h_, l_;
          split2(v, h_, l_);
          Chi[(size_t)row * N + col] = (short)h_;
          Clo[(size_t)row * N + col] = (short)l_;
        }
      }
}

// ---------------------------------------------------------------------------
// MFMA causal flash attention, pre-split bf16 inputs (fp32-class numerics).
// Structure identical to the measured round-12 kernel (4 decoupled waves,
// wave-private P LDS, no __syncthreads); ONLY the load paths changed:
// Q/K from qkvh/qkvl (split-bf16, straight short8 loads), V from the
// pre-transposed Vt[b][h][d][s] (contiguous short8). The 1/sqrt(HD) scale
// is applied to fp32 scores post-MFMA (exact pow2). qb reversed so the
// longest blocks dispatch first.
// ---------------------------------------------------------------------------
#define KT2 32
__global__ __launch_bounds__(256) void attn_mfma(
    const short* __restrict__ qkvh, const short* __restrict__ qkvl,
    const short* __restrict__ vth, const short* __restrict__ vtl,
    float* __restrict__ out) {
  int qb = gridDim.x - 1 - blockIdx.x;  // long blocks first
  int h = blockIdx.y, b = blockIdx.z;
  int tid = threadIdx.x;
  int wv = tid >> 6, lane = tid & 63;
  int lr = lane & 15;   // frag row (A) / col (B/D)
  int lg = lane >> 4;   // 0..3: k-group (frags), row-group (C/D)

  __shared__ short P_hi[4][16][40];  // wave-private P tiles (pad 40)
  __shared__ short P_lo[4][16][40];

  int q0 = qb * 64 + wv * 16;

  // ---- Q A-frags (2 d-chunks), raw units ----
  short8 qh[2], ql[2];
  {
    const short* qp  = qkvh + (size_t)(b * SEQ + q0 + lr) * 3072 + h * HD + lg * 8;
    const short* qpl = qkvl + (size_t)(b * SEQ + q0 + lr) * 3072 + h * HD + lg * 8;
    qh[0] = *(const short8*)qp;
    qh[1] = *(const short8*)(qp + 32);
    ql[0] = *(const short8*)qpl;
    ql[1] = *(const short8*)(qpl + 32);
  }

  floatx4 o_acc[4];
#pragma unroll
  for (int df = 0; df < 4; df++) o_acc[df] = (floatx4){0.f, 0.f, 0.f, 0.f};
  float m_st[4] = {-1e30f, -1e30f, -1e30f, -1e30f};
  float l_st[4] = {0.f, 0.f, 0.f, 0.f};

  const short* kbh = qkvh + (size_t)(b * SEQ) * 3072 + 1024 + h * HD + lg * 8;
  const short* kbl = qkvl + (size_t)(b * SEQ) * 3072 + 1024 + h * HD + lg * 8;
  const short* vbh = vth + ((size_t)((b * NHEAD + h) * HD)) * SEQ;
  const short* vbl = vtl + ((size_t)((b * NHEAD + h) * HD)) * SEQ;

  int ntiles = (q0 + 15) / KT2 + 1;  // covers keys <= wave's max q

  for (int t = 0; t < ntiles; t++) {
    int k0 = t * KT2;

    // ---- K B-frags: straight short8 loads ----
    short8 kh[2][2], kl[2][2];
#pragma unroll
    for (int kf = 0; kf < 2; kf++) {
      const short* kp  = kbh + (size_t)(k0 + kf * 16 + lr) * 3072;
      const short* kpl = kbl + (size_t)(k0 + kf * 16 + lr) * 3072;
      kh[kf][0] = *(const short8*)kp;
      kh[kf][1] = *(const short8*)(kp + 32);
      kl[kf][0] = *(const short8*)kpl;
      kl[kf][1] = *(const short8*)(kpl + 32);
    }

    // ---- QK^T (C/D: row=q=lg*4+r, col=key=kf*16+lr) ----
    floatx4 s[2];
#pragma unroll
    for (int kf = 0; kf < 2; kf++) {
      floatx4 acc = (floatx4){0.f, 0.f, 0.f, 0.f};
#pragma unroll
      for (int dc = 0; dc < 2; dc++) {
        acc = __builtin_amdgcn_mfma_f32_16x16x32_bf16(qh[dc], kh[kf][dc], acc, 0, 0, 0);
        acc = __builtin_amdgcn_mfma_f32_16x16x32_bf16(qh[dc], kl[kf][dc], acc, 0, 0, 0);
        acc = __builtin_amdgcn_mfma_f32_16x16x32_bf16(ql[dc], kh[kf][dc], acc, 0, 0, 0);
      }
      s[kf] = acc;
    }

    // ---- scale + causal mask + row-max (16-lane col group) ----
    float tmax[4];
#pragma unroll
    for (int r = 0; r < 4; r++) {
      int qg = q0 + lg * 4 + r;
#pragma unroll
      for (int kf = 0; kf < 2; kf++) {
        s[kf][r] *= 0.125f;  // HD^-0.5
        if (k0 + kf * 16 + lr > qg) s[kf][r] = -3.0e38f;
      }
      tmax[r] = fmaxf(s[0][r], s[1][r]);
    }
#pragma unroll
    for (int off = 1; off < 16; off <<= 1)
#pragma unroll
      for (int r = 0; r < 4; r++)
        tmax[r] = fmaxf(tmax[r], __shfl_xor(tmax[r], off));

    // ---- online softmax update ----
    float p0[4], p1[4];
#pragma unroll
    for (int r = 0; r < 4; r++) {
      float mn = fmaxf(m_st[r], tmax[r]);
      float sc = __expf(m_st[r] - mn);
      m_st[r] = mn;
      p0[r] = __expf(s[0][r] - mn);
      p1[r] = __expf(s[1][r] - mn);
      l_st[r] = l_st[r] * sc + p0[r] + p1[r];
#pragma unroll
      for (int df = 0; df < 4; df++) o_acc[df][r] *= sc;
    }

    // ---- P (C/D layout) -> wave-private LDS as split bf16 ----
#pragma unroll
    for (int r = 0; r < 4; r++) {
      unsigned short h_, l_;
      split2(p0[r], h_, l_);
      P_hi[wv][lg * 4 + r][lr] = (short)h_;
      P_lo[wv][lg * 4 + r][lr] = (short)l_;
      split2(p1[r], h_, l_);
      P_hi[wv][lg * 4 + r][16 + lr] = (short)h_;
      P_lo[wv][lg * 4 + r][16 + lr] = (short)l_;
    }
    // ---- read back as A-frag (same-wave RAW: compiler lgkmcnt) ----
    short8 ph = *(const short8*)&P_hi[wv][lr][lg * 8];
    short8 pl = *(const short8*)&P_lo[wv][lr][lg * 8];

    // ---- V B-frags: contiguous short8 from Vt + PV ----
#pragma unroll
    for (int df = 0; df < 4; df++) {
      const short* vp  = vbh + (size_t)(df * 16 + lr) * SEQ + k0 + lg * 8;
      const short* vpl = vbl + (size_t)(df * 16 + lr) * SEQ + k0 + lg * 8;
      short8 vh = *(const short8*)vp;
      short8 vl = *(const short8*)vpl;
      o_acc[df] = __builtin_amdgcn_mfma_f32_16x16x32_bf16(ph, vh, o_acc[df], 0, 0, 0);
      o_acc[df] = __builtin_amdgcn_mfma_f32_16x16x32_bf16(ph, vl, o_acc[df], 0, 0, 0);
      o_acc[df] = __builtin_amdgcn_mfma_f32_16x16x32_bf16(pl, vh, o_acc[df], 0, 0, 0);
    }
  }

  // ---- final l row-sum across the 16-lane col group ----
#pragma unroll
  for (int off = 1; off < 16; off <<= 1)
#pragma unroll
    for (int r = 0; r < 4; r++)
      l_st[r] += __shfl_xor(l_st[r], off);

  // ---- write O (C/D layout -> concat-head fp32) ----
#pragma unroll
  for (int r = 0; r < 4; r++) {
    float inv = 1.f / l_st[r];
    float* op = out + (size_t)(b * SEQ + q0 + lg * 4 + r) * DMODEL + h * HD;
#pragma unroll
    for (int df = 0; df < 4; df++)
      op[df * 16 + lr] = o_acc[df][r] * inv;
  }
}

// ---------------------------------------------------------------------------
// Orchestration
// ---------------------------------------------------------------------------
extern "C" void kernel_launch(void* const* d_in, const int* in_sizes, int n_in,
                              void* d_out, int out_size, void* d_ws, size_t ws_size,
                              hipStream_t stream) {
  const float* x     = (const float*)d_in[0];
  const float* Wq    = (const float*)d_in[1];
  const float* Wk    = (const float*)d_in[2];
  const float* Wv    = (const float*)d_in[3];
  const float* Wp    = (const float*)d_in[4];
  const float* bp    = (const float*)d_in[5];
  const float* W1    = (const float*)d_in[6];
  const float* b1    = (const float*)d_in[7];
  const float* W2    = (const float*)d_in[8];
  const float* b2    = (const float*)d_in[9];
  const float* g1    = (const float*)d_in[10];
  const float* beta1 = (const float*)d_in[11];
  const float* g2    = (const float*)d_in[12];
  const float* beta2 = (const float*)d_in[13];
  float* out = (float*)d_out;

  // Workspace layout with liveness (peak 96,468,992 B). x1 lives in d_out.
  char* ws = (char*)d_ws;
  short* h_hi     = (short*)(ws + 0);          //  8 MiB, live steps 1-3
  short* h_lo     = (short*)(ws + 8388608);    //  8 MiB
  short* WcT_hi   = (short*)(ws + 16777216);   //  6 MiB, live 2-3
  short* WcT_lo   = (short*)(ws + 23068672);   //  6 MiB
  short* qkvh     = (short*)(ws + 29360128);   // 24 MiB, live 3-4
  short* qkvl     = (short*)(ws + 54525952);   // 24 MiB (ends 79,691,776)
  short* vth      = (short*)(ws + 79691776);   //  8 MiB, live 3b-4
  short* vtl      = (short*)(ws + 88080384);   //  8 MiB (ends 96,468,992)
  float* attno    = (float*)(ws + 0);          // 16 MiB fp32, live 4-4b (h dead)
  short* at_hi    = (short*)(ws + 16777216);   //  8 MiB, live 4b-6 (WcT dead)
  short* at_lo    = (short*)(ws + 25165824);   //  8 MiB (qkvh dead after 4)
  short* WpT_hi   = (short*)(ws + 33554432);   //  2 MiB, live 5-6
  short* WpT_lo   = (short*)(ws + 35651584);   //  2 MiB
  short* h2_hi    = (short*)(ws + 0);          //  8 MiB, live 7-9 (attno dead)
  short* h2_lo    = (short*)(ws + 8388608);    //  8 MiB
  short* W1T_hi   = (short*)(ws + 16777216);   //  8 MiB, live 8-9 (at dead)
  short* W1T_lo   = (short*)(ws + 25165824);   //  8 MiB
  short* ffn_hi   = (short*)(ws + 33554432);   // 32 MiB, live 9-11 (qkvl/vt/WpT dead)
  short* ffn_lo   = (short*)(ws + 67108864);   // 32 MiB (ends 100,663,296)
  short* W2T_hi   = (short*)(ws + 0);          //  8 MiB, live 10-11 (h2 dead)
  short* W2T_lo   = (short*)(ws + 8388608);    //  8 MiB
  float* x1       = out;

  // 1. LN1 -> split bf16
  ln_split<<<NTOK, 256, 0, stream>>>(x, g1, beta1, h_hi, h_lo);
  // 2. QKV weights: transpose+split -> [3072][1024]
  repack_qkvT<<<(3072 * 1024) / 256, 256, 0, stream>>>(Wq, Wk, Wv, WcT_hi, WcT_lo);
  // 3. qkv = h @ Wc  -> split-bf16 qkvh/qkvl
  gemm_mfma<3><<<dim3(3072 / 128, NTOK / 128), 256, 0, stream>>>(
      h_hi, h_lo, WcT_hi, WcT_lo, nullptr, nullptr, nullptr, qkvh, qkvl,
      NTOK, 3072, DMODEL);
  // 3b. transpose V section -> Vt[b][h][d][s]
  vt_transpose<<<dim3(SEQ / 64, NHEAD, BATCH), 256, 0, stream>>>(qkvh, qkvl, vth, vtl);
  // 4. MFMA attention -> fp32 attno (concat-head layout)
  attn_mfma<<<dim3(SEQ / 64, NHEAD, BATCH), 256, 0, stream>>>(qkvh, qkvl, vth, vtl, attno);
  // 4b. split attno -> bf16 hi/lo
  split_rows<<<(NTOK * DMODEL) / 1024, 256, 0, stream>>>(attno, at_hi, at_lo);
  // 5. Wp: transpose+split -> [1024][1024]
  transpose_split<<<(1024 * 1024) / 256, 256, 0, stream>>>(Wp, WpT_hi, WpT_lo, 10, DMODEL);
  // 6. x1 = x + attno @ Wp + bp  (fp32, into d_out)
  gemm_mfma<1><<<dim3(DMODEL / 128, NTOK / 128), 256, 0, stream>>>(
      at_hi, at_lo, WpT_hi, WpT_lo, bp, x, x1, nullptr, nullptr,
      NTOK, DMODEL, DMODEL);
  // 7. LN2 -> split bf16
  ln_split<<<NTOK, 256, 0, stream>>>(x1, g2, beta2, h2_hi, h2_lo);
  // 8. W1: transpose+split -> [4096][1024]
  transpose_split<<<(1024 * 4096) / 256, 256, 0, stream>>>(W1, W1T_hi, W1T_lo, 10, DFF);
  // 9. ffn = relu(h2 @ W1 + b1) -> split bf16
  gemm_mfma<2><<<dim3(DFF / 128, NTOK / 128), 256, 0, stream>>>(
      h2_hi, h2_lo, W1T_hi, W1T_lo, b1, nullptr, nullptr, ffn_hi, ffn_lo,
      NTOK, DFF, DMODEL);
  // 10. W2: transpose+split -> [1024][4096]
  transpose_split<<<(4096 * 1024) / 256, 256, 0, stream>>>(W2, W2T_hi, W2T_lo, 12, DMODEL);
  // 11. out = x1 + ffn @ W2 + b2  (fp32, res==out aliased per-element)
  gemm_mfma<1><<<dim3(DMODEL / 128, NTOK / 128), 256, 0, stream>>>(
      ffn_hi, ffn_lo, W2T_hi, W2T_lo, b2, x1, out, nullptr, nullptr,
      NTOK, DMODEL, DFF);
}